// Round 2
// baseline (927.201 us; speedup 1.0000x reference)
//
#include <hip/hip_runtime.h>

// Tanh-RNN: B=8192, T=2048, I=2, H=20, FC(H->1) on last h.
// Round 9: dual-row-per-lane ILP. R8 post-mortem: removing DPP movs was
// neutral -> the 24% VALU-idle (VALUBusy 76% at 1 wave/SIMD) is dependency
// stall in the serial tanh->butterfly->FMA section, and all 8 rows of a wave
// are in lockstep (different octets, same instruction stream) so nothing
// fills it. Fix: each octet now owns TWO independent rows (16 rows/wave,
// 512 blocks -> 2 SIMDs/CU active). Stream B's FMAs fill stream A's
// tanh/DPP latency at the instruction level. Per-row issue count unchanged
// (W_hh regs shared, loop overhead amortized); wall/step ~= busy-cycles.
// Scheme otherwise identical to R8: j-split (8 lanes/row, 3 j/lane),
// h-allgather in VALU DPP (mir7 -> xor1 -> xor2, 21 DPPs/row), no LDS.

#define T_STEPS 2048
#define B_ROWS  8192
// chunk = 2 float4 = 4 steps of x per row-stream; loop does 2 chunks/iter.
#define NCHUNK  (T_STEPS / 4)

#define XOR1_CTRL 0xB1   // quad_perm(1,0,3,2): lane^1
#define XOR2_CTRL 0x4E   // quad_perm(2,3,0,1): lane^2
#define MIR7_CTRL 0x141  // row_half_mirror: lane^7 within each 8-lane octet

__device__ __forceinline__ float tanh_fast(float a) {
    // tanh(a) = 1 - 2/(exp(2a)+1); exp(2a)=exp2(a*2*log2e). Saturates correctly.
    float e = __builtin_amdgcn_exp2f(a * 2.8853900817779268f);
    float r = __builtin_amdgcn_rcpf(e + 1.0f);
    return fmaf(-2.0f, r, 1.0f);
}

__device__ __forceinline__ float2 fma2(float2 a, float2 b, float2 c) {
    return make_float2(fmaf(a.x, b.x, c.x), fmaf(a.y, b.y, c.y));
}

// In-place DPP: dst = dpp(src). old is tied to dst (dead value) -> no mov.
template <int CTRL>
__device__ __forceinline__ void dpp_to(float& dst, float src) {
    dst = __int_as_float(__builtin_amdgcn_update_dpp(
        __float_as_int(dst), __float_as_int(src), CTRL, 0xF, 0xF, false));
}

// Epilogue-only variant (old=0, bound_ctrl=true) -- executed once.
template <int CTRL>
__device__ __forceinline__ float dpp_full(float v) {
    return __int_as_float(__builtin_amdgcn_update_dpp(
        0, __float_as_int(v), CTRL, 0xF, 0xF, true));
}

__global__ __launch_bounds__(64, 1) void rnn_fused(
    const float* __restrict__ x,      // [B, T, 2]
    const float* __restrict__ W_ih,   // [20, 2]
    const float* __restrict__ W_hh,   // [20, 20]
    const float* __restrict__ b_ih,   // [20]
    const float* __restrict__ b_hh,   // [20]
    const float* __restrict__ fc_w,   // [1, 20]
    const float* __restrict__ fc_b,   // [1]
    float* __restrict__ out)          // [8192] out, then [8192*20] h_state
{
    const int lane = threadIdx.x & 63;
    const int g    = lane & 7;        // owns j = 3g..3g+2
    const int r    = lane >> 3;       // octet index within wave
    const int rowA = blockIdx.x * 16 + r;      // stream A row
    const int rowB = rowA + 8;                 // stream B row (independent)

    // Butterfly slot order: after stages (mir7, xor1, xor2), the lane's
    // 24-slot h vector holds triplets of g' = g ^ M[slot/3]:
    const int M[8] = {0, 7, 1, 6, 2, 5, 3, 4};

    float2 W2[3][12];                 // pair p covers slots 2p, 2p+1 (shared A/B)
    float  wi0[3], wi1[3], bsum[3], fcw[3];
#pragma unroll
    for (int jj = 0; jj < 3; ++jj) {
        const int j = 3 * g + jj;
        const bool v = (j < 20);
#pragma unroll
        for (int p = 0; p < 12; ++p) {
            float wv[2];
#pragma unroll
            for (int h = 0; h < 2; ++h) {
                const int slot = 2 * p + h;
                const int k = 3 * (g ^ M[slot / 3]) + (slot % 3);
                wv[h] = (v && k < 20) ? W_hh[j * 20 + k] : 0.0f;
            }
            W2[jj][p] = make_float2(wv[0], wv[1]);
        }
        wi0[jj]  = v ? W_ih[j * 2 + 0] : 0.0f;
        wi1[jj]  = v ? W_ih[j * 2 + 1] : 0.0f;
        bsum[jj] = v ? (b_ih[j] + b_hh[j]) : 0.0f;
        fcw[jj]  = v ? fc_w[j] : 0.0f;
    }

    float hgA[24], hgB[24];           // gathered h, butterfly slot order
#pragma unroll
    for (int i = 0; i < 24; ++i) { hgA[i] = 0.0f; hgB[i] = 0.0f; }

    auto step = [&](float a0, float a1, float b0, float b1) {
        float2 cA0 = make_float2(fmaf(a0, wi0[0], bsum[0]), a1 * wi1[0]);
        float2 cA1 = make_float2(fmaf(a0, wi0[1], bsum[1]), a1 * wi1[1]);
        float2 cA2 = make_float2(fmaf(a0, wi0[2], bsum[2]), a1 * wi1[2]);
        float2 cB0 = make_float2(fmaf(b0, wi0[0], bsum[0]), b1 * wi1[0]);
        float2 cB1 = make_float2(fmaf(b0, wi0[1], bsum[1]), b1 * wi1[1]);
        float2 cB2 = make_float2(fmaf(b0, wi0[2], bsum[2]), b1 * wi1[2]);
#pragma unroll
        for (int p = 0; p < 12; ++p) {
            const float2 hpA = make_float2(hgA[2 * p], hgA[2 * p + 1]);
            const float2 hpB = make_float2(hgB[2 * p], hgB[2 * p + 1]);
            cA0 = fma2(hpA, W2[0][p], cA0);
            cB0 = fma2(hpB, W2[0][p], cB0);
            cA1 = fma2(hpA, W2[1][p], cA1);
            cB1 = fma2(hpB, W2[1][p], cB1);
            cA2 = fma2(hpA, W2[2][p], cA2);
            cB2 = fma2(hpB, W2[2][p], cB2);
        }
        hgA[0] = tanh_fast(cA0.x + cA0.y);
        hgB[0] = tanh_fast(cB0.x + cB0.y);
        hgA[1] = tanh_fast(cA1.x + cA1.y);
        hgB[1] = tanh_fast(cB1.x + cB1.y);
        hgA[2] = tanh_fast(cA2.x + cA2.y);
        hgB[2] = tanh_fast(cB2.x + cB2.y);
        // ---- DPP butterfly allgather, A/B interleaved ----
        dpp_to<MIR7_CTRL>(hgA[3], hgA[0]);
        dpp_to<MIR7_CTRL>(hgB[3], hgB[0]);
        dpp_to<MIR7_CTRL>(hgA[4], hgA[1]);
        dpp_to<MIR7_CTRL>(hgB[4], hgB[1]);
        dpp_to<MIR7_CTRL>(hgA[5], hgA[2]);
        dpp_to<MIR7_CTRL>(hgB[5], hgB[2]);
#pragma unroll
        for (int i = 0; i < 6; ++i) {
            dpp_to<XOR1_CTRL>(hgA[6 + i], hgA[i]);
            dpp_to<XOR1_CTRL>(hgB[6 + i], hgB[i]);
        }
#pragma unroll
        for (int i = 0; i < 12; ++i) {
            dpp_to<XOR2_CTRL>(hgA[12 + i], hgA[i]);
            dpp_to<XOR2_CTRL>(hgB[12 + i], hgB[i]);
        }
    };

    // x: per 4-step chunk, 2 float4 per lane per stream (octet shares the
    // cacheline, L1 broadcast); double-buffered one chunk ahead, ping-pong.
    const float4* xqA = (const float4*)(x + (size_t)rowA * (T_STEPS * 2));
    const float4* xqB = (const float4*)(x + (size_t)rowB * (T_STEPS * 2));
    float4 qA[2], qnA[2], qB[2], qnB[2];
#pragma unroll
    for (int i = 0; i < 2; ++i) { qA[i] = xqA[i]; qB[i] = xqB[i]; }

#pragma unroll 1
    for (int c = 0; c < NCHUNK; c += 2) {
        const int c1 = c + 1;                                  // qn <- chunk c+1
        const int c2 = (c + 2 < NCHUNK) ? (c + 2) : c1;        // q  <- chunk c+2
#pragma unroll
        for (int i = 0; i < 2; ++i) {
            qnA[i] = xqA[2 * c1 + i];
            qnB[i] = xqB[2 * c1 + i];
        }

        step(qA[0].x, qA[0].y, qB[0].x, qB[0].y);
        step(qA[0].z, qA[0].w, qB[0].z, qB[0].w);
        step(qA[1].x, qA[1].y, qB[1].x, qB[1].y);
        step(qA[1].z, qA[1].w, qB[1].z, qB[1].w);

#pragma unroll
        for (int i = 0; i < 2; ++i) {
            qA[i] = xqA[2 * c2 + i];
            qB[i] = xqB[2 * c2 + i];
        }

        step(qnA[0].x, qnA[0].y, qnB[0].x, qnB[0].y);
        step(qnA[0].z, qnA[0].w, qnB[0].z, qnB[0].w);
        step(qnA[1].x, qnA[1].y, qnB[1].x, qnB[1].y);
        step(qnA[1].z, qnA[1].w, qnB[1].z, qnB[1].w);
    }

    // ---- epilogue ----
    // h_state: [1, B, H] flat at offset B_ROWS; lane stores its own 3 j's
    {
        const int j0 = 3 * g;
        float* hsA = out + B_ROWS + (size_t)rowA * 20;
        float* hsB = out + B_ROWS + (size_t)rowB * 20;
        if (j0 + 0 < 20) { hsA[j0 + 0] = hgA[0]; hsB[j0 + 0] = hgB[0]; }
        if (j0 + 1 < 20) { hsA[j0 + 1] = hgA[1]; hsB[j0 + 1] = hgB[1]; }
        if (j0 + 2 < 20) { hsA[j0 + 2] = hgA[2]; hsB[j0 + 2] = hgB[2]; }
    }
    // FC: per-lane partial over own j's, octet tree-reduce (xor1,xor2,mir7)
    {
        float pA = hgA[0] * fcw[0];
        pA = fmaf(hgA[1], fcw[1], pA);
        pA = fmaf(hgA[2], fcw[2], pA);
        float pB = hgB[0] * fcw[0];
        pB = fmaf(hgB[1], fcw[1], pB);
        pB = fmaf(hgB[2], fcw[2], pB);
        pA += dpp_full<XOR1_CTRL>(pA);
        pB += dpp_full<XOR1_CTRL>(pB);
        pA += dpp_full<XOR2_CTRL>(pA);
        pB += dpp_full<XOR2_CTRL>(pB);
        pA += dpp_full<MIR7_CTRL>(pA);
        pB += dpp_full<MIR7_CTRL>(pB);
        if (g == 0) {
            out[rowA] = pA + fc_b[0];
            out[rowB] = pB + fc_b[0];
        }
    }
}

extern "C" void kernel_launch(void* const* d_in, const int* in_sizes, int n_in,
                              void* d_out, int out_size, void* d_ws, size_t ws_size,
                              hipStream_t stream) {
    const float* x    = (const float*)d_in[0];
    const float* W_ih = (const float*)d_in[1];
    const float* W_hh = (const float*)d_in[2];
    const float* b_ih = (const float*)d_in[3];
    const float* b_hh = (const float*)d_in[4];
    const float* fc_w = (const float*)d_in[5];
    const float* fc_b = (const float*)d_in[6];
    float* out = (float*)d_out;

    // 512 blocks x 64 threads: 1 wave/block, 16 rows/wave (2 independent
    // row-streams per lane) -> 2 SIMDs/CU active, stalls filled by ILP.
    rnn_fused<<<512, 64, 0, stream>>>(x, W_ih, W_hh, b_ih, b_hh, fc_w, fc_b, out);
}

// Round 4
// 736.373 us; speedup vs baseline: 1.2591x; 1.2591x over previous
//
#include <hip/hip_runtime.h>

// Tanh-RNN: B=8192, T=2048, I=2, H=20, FC(H->1) on last h.
// Round 11 == Round 10 resubmitted (container infra failure, no kernel signal).
// Layout: R8's j-split (8 lanes/row, 3 j/lane, 8 rows/wave, 1024 waves = 1
// per SIMD). Change vs R8: h-allgather moved from the 21-op VALU DPP
// butterfly to 21 ds_bpermute_b32 on the LDS-crossbar pipe:
//  - no VALU issue slots consumed, no DPP RAW-hazard wait states,
//  - executes CONCURRENTLY with the next step's 72-FMA block,
//  - no LDS storage / barriers (bpermute is a pure crossbar pull),
//  - octet-local pattern: stays in the same 32-lane half and is a bank
//    permutation (conflict-free).
// Slot layout: consumption order == bpermute issue order:
//   slots 0..2   = own j (3g..3g+2), ready at tanh
//   slots 3..9   = jj=0 of groups g^1..g^7   (issued right after tanh0)
//   slots 10..16 = jj=1 of groups g^1..g^7   (after tanh1)
//   slots 17..23 = jj=2 of groups g^1..g^7   (after tanh2)
// so progressive lgkmcnt waits pipeline: only the first gathered slot has
// exposed latency; the rest arrive faster than the FMA pairs consume them.

#define T_STEPS 2048
#define B_ROWS  8192
#define NCHUNK  (T_STEPS / 8)

#define XOR1_CTRL 0xB1   // quad_perm(1,0,3,2): lane^1
#define XOR2_CTRL 0x4E   // quad_perm(2,3,0,1): lane^2
#define MIR7_CTRL 0x141  // row_half_mirror: lane^7 within each 8-lane octet

__device__ __forceinline__ float tanh_fast(float a) {
    // tanh(a) = 1 - 2/(exp(2a)+1); exp(2a)=exp2(a*2*log2e). Saturates correctly.
    float e = __builtin_amdgcn_exp2f(a * 2.8853900817779268f);
    float r = __builtin_amdgcn_rcpf(e + 1.0f);
    return fmaf(-2.0f, r, 1.0f);
}

__device__ __forceinline__ float2 fma2(float2 a, float2 b, float2 c) {
    return make_float2(fmaf(a.x, b.x, c.x), fmaf(a.y, b.y, c.y));
}

// Epilogue-only DPP reduce helper (executed once).
template <int CTRL>
__device__ __forceinline__ float dpp_full(float v) {
    return __int_as_float(__builtin_amdgcn_update_dpp(
        0, __float_as_int(v), CTRL, 0xF, 0xF, true));
}

// LDS-crossbar pull: dst lane gets src value of lane (addr/4). No storage.
__device__ __forceinline__ float bperm(int addr, float v) {
    return __int_as_float(__builtin_amdgcn_ds_bpermute(addr, __float_as_int(v)));
}

__global__ __launch_bounds__(64, 1) void rnn_fused(
    const float* __restrict__ x,      // [B, T, 2]
    const float* __restrict__ W_ih,   // [20, 2]
    const float* __restrict__ W_hh,   // [20, 20]
    const float* __restrict__ b_ih,   // [20]
    const float* __restrict__ b_hh,   // [20]
    const float* __restrict__ fc_w,   // [1, 20]
    const float* __restrict__ fc_b,   // [1]
    float* __restrict__ out)          // [8192] out, then [8192*20] h_state
{
    const int lane = threadIdx.x & 63;
    const int g    = lane & 7;        // owns j = 3g..3g+2
    const int r    = lane >> 3;       // row within wave
    const int row  = blockIdx.x * 8 + r;

    // bpermute source-lane addresses for masks m=1..7 (loop-invariant).
    // addr = 4 * (same octet, group g^m); octet never crosses the 32-boundary.
    int am[7];
#pragma unroll
    for (int q = 0; q < 7; ++q)
        am[q] = (((lane & 56) | ((lane & 7) ^ (q + 1))) << 2);

    float2 W2[3][12];                 // pair p covers slots 2p, 2p+1 of hg[]
    float  wi0[3], wi1[3], bsum[3], fcw[3];
#pragma unroll
    for (int jj = 0; jj < 3; ++jj) {
        const int j = 3 * g + jj;
        const bool v = (j < 20);
#pragma unroll
        for (int p = 0; p < 12; ++p) {
            float wv[2];
#pragma unroll
            for (int h = 0; h < 2; ++h) {
                const int slot = 2 * p + h;
                // slot -> (mask m, source jj kk): see layout in header comment
                int m, kk;
                if (slot < 3)       { m = 0;         kk = slot; }
                else if (slot < 10) { m = slot - 2;  kk = 0; }
                else if (slot < 17) { m = slot - 9;  kk = 1; }
                else                { m = slot - 16; kk = 2; }
                const int k = 3 * (g ^ m) + kk;
                wv[h] = (v && k < 20) ? W_hh[j * 20 + k] : 0.0f;
            }
            W2[jj][p] = make_float2(wv[0], wv[1]);
        }
        wi0[jj]  = v ? W_ih[j * 2 + 0] : 0.0f;
        wi1[jj]  = v ? W_ih[j * 2 + 1] : 0.0f;
        bsum[jj] = v ? (b_ih[j] + b_hh[j]) : 0.0f;
        fcw[jj]  = v ? fc_w[j] : 0.0f;
    }

    float hg[24];                     // gathered h in slot order above
#pragma unroll
    for (int i = 0; i < 24; ++i) hg[i] = 0.0f;

    auto step = [&](float x0, float x1) {
        float2 c0 = make_float2(fmaf(x0, wi0[0], bsum[0]), x1 * wi1[0]);
        float2 c1 = make_float2(fmaf(x0, wi0[1], bsum[1]), x1 * wi1[1]);
        float2 c2 = make_float2(fmaf(x0, wi0[2], bsum[2]), x1 * wi1[2]);
#pragma unroll
        for (int p = 0; p < 12; ++p) {
            const float2 hp = make_float2(hg[2 * p], hg[2 * p + 1]);
            c0 = fma2(hp, W2[0][p], c0);
            c1 = fma2(hp, W2[1][p], c1);
            c2 = fma2(hp, W2[2][p], c2);
        }
        // tanh + allgather: issue each jj's 7 bpermutes as soon as its tanh
        // result exists; DS pipe runs them under the next step's FMA block.
        hg[0] = tanh_fast(c0.x + c0.y);
#pragma unroll
        for (int q = 0; q < 7; ++q) hg[3 + q]  = bperm(am[q], hg[0]);
        hg[1] = tanh_fast(c1.x + c1.y);
#pragma unroll
        for (int q = 0; q < 7; ++q) hg[10 + q] = bperm(am[q], hg[1]);
        hg[2] = tanh_fast(c2.x + c2.y);
#pragma unroll
        for (int q = 0; q < 7; ++q) hg[17 + q] = bperm(am[q], hg[2]);
    };

    // x: per 8-step chunk, 4 float4 per lane (octet shares the cacheline, L1
    // broadcast); double-buffered one chunk ahead, ping-pong q/qn (no copies).
    const float4* xq = (const float4*)(x + (size_t)row * (T_STEPS * 2));
    float4 q[4], qn[4];
#pragma unroll
    for (int i = 0; i < 4; ++i) q[i] = xq[i];

#pragma unroll 1
    for (int c = 0; c < NCHUNK; c += 2) {
        const int c1 = c + 1;                                  // qn <- chunk c+1
        const int c2 = (c + 2 < NCHUNK) ? (c + 2) : c1;        // q  <- chunk c+2
#pragma unroll
        for (int i = 0; i < 4; ++i) qn[i] = xq[4 * c1 + i];

        step(q[0].x, q[0].y); step(q[0].z, q[0].w);
        step(q[1].x, q[1].y); step(q[1].z, q[1].w);
        step(q[2].x, q[2].y); step(q[2].z, q[2].w);
        step(q[3].x, q[3].y); step(q[3].z, q[3].w);

#pragma unroll
        for (int i = 0; i < 4; ++i) q[i] = xq[4 * c2 + i];

        step(qn[0].x, qn[0].y); step(qn[0].z, qn[0].w);
        step(qn[1].x, qn[1].y); step(qn[1].z, qn[1].w);
        step(qn[2].x, qn[2].y); step(qn[2].z, qn[2].w);
        step(qn[3].x, qn[3].y); step(qn[3].z, qn[3].w);
    }

    // ---- epilogue ----
    // h_state: [1, B, H] flat at offset B_ROWS; lane stores its own 3 j's
    // (slots 0..2 hold own j values).
    {
        const int j0 = 3 * g;
        float* hs = out + B_ROWS + (size_t)row * 20;
        if (j0 + 0 < 20) hs[j0 + 0] = hg[0];
        if (j0 + 1 < 20) hs[j0 + 1] = hg[1];
        if (j0 + 2 < 20) hs[j0 + 2] = hg[2];
    }
    // FC: per-lane partial over own j's, octet tree-reduce (xor1,xor2,mir7)
    {
        float p = hg[0] * fcw[0];
        p = fmaf(hg[1], fcw[1], p);
        p = fmaf(hg[2], fcw[2], p);
        p += dpp_full<XOR1_CTRL>(p);
        p += dpp_full<XOR2_CTRL>(p);
        p += dpp_full<MIR7_CTRL>(p);
        if (g == 0) out[row] = p + fc_b[0];
    }
}

extern "C" void kernel_launch(void* const* d_in, const int* in_sizes, int n_in,
                              void* d_out, int out_size, void* d_ws, size_t ws_size,
                              hipStream_t stream) {
    const float* x    = (const float*)d_in[0];
    const float* W_ih = (const float*)d_in[1];
    const float* W_hh = (const float*)d_in[2];
    const float* b_ih = (const float*)d_in[3];
    const float* b_hh = (const float*)d_in[4];
    const float* fc_w = (const float*)d_in[5];
    const float* fc_b = (const float*)d_in[6];
    float* out = (float*)d_out;

    // 1024 blocks x 64 threads: 1 wave/block, 8 rows/wave -> 1 wave/SIMD
    rnn_fused<<<1024, 64, 0, stream>>>(x, W_ih, W_hh, b_ih, b_hh, fc_w, fc_b, out);
}

// Round 5
// 642.428 us; speedup vs baseline: 1.4433x; 1.1462x over previous
//
#include <hip/hip_runtime.h>

// Tanh-RNN: B=8192, T=2048, I=2, H=20, FC(H->1) on last h.
// Round 12: fold the h-allgather INTO the FMAs via DPP-modified v_fmac_f32.
// R8 layout kept (8 lanes/row, 3 j/lane, 8 rows/wave, 1024 waves = 1/SIMD).
// R10/11 lesson: DS-pipe bpermute gather = +36% (latency on the critical
// recurrence path). R8's cost model: 21 standalone v_mov_b32_dpp in a
// depth-3 tree + RAW-hazard nops. Here: each lane keeps own h[3] and
// g4[3] = h from lane^4 (masked row_shl/shr pair, R7-verified); all other
// source groups are reached by quad_perm DPP modifiers ON the fmac itself:
//   m=0: plain fmac(h)        m=4: plain fmac(g4)
//   m=1,2,3: fmac_dpp quad_perm ^1/^2/^3 on h
//   m=5,6,7: fmac_dpp quad_perm ^1/^2/^3 on g4   ((g^4)^qm = g^(4+qm))
// 21 DPP movs + 3 adds -> 6 DPP movs; 54/72 fmacs carry a free modifier.
// Hazard discipline (DPP reading a VGPR needs ~2 instrs after its VALU
// write): program order puts 6 c-inits + 18 plain fmacs between tanh/g4
// writes and the first asm dpp reader.

#define T_STEPS 2048
#define B_ROWS  8192
#define NCHUNK  (T_STEPS / 8)

#define XOR1_CTRL 0xB1   // quad_perm(1,0,3,2): lane^1
#define XOR2_CTRL 0x4E   // quad_perm(2,3,0,1): lane^2
#define MIR7_CTRL 0x141  // row_half_mirror: lane^7 within each 8-lane octet

__device__ __forceinline__ float tanh_fast(float a) {
    // tanh(a) = 1 - 2/(exp(2a)+1); exp(2a)=exp2(a*2*log2e). Saturates correctly.
    float e = __builtin_amdgcn_exp2f(a * 2.8853900817779268f);
    float r = __builtin_amdgcn_rcpf(e + 1.0f);
    return fmaf(-2.0f, r, 1.0f);
}

// Epilogue-only DPP reduce helper (executed once).
template <int CTRL>
__device__ __forceinline__ float dpp_full(float v) {
    return __int_as_float(__builtin_amdgcn_update_dpp(
        0, __float_as_int(v), CTRL, 0xF, 0xF, true));
}

// lane^4 within each 8-lane octet (R7-verified direction):
//   lanes 0-3, 8-11  (banks 0,2): need src L+4 -> row_shl:4 (0x104)
//   lanes 4-7, 12-15 (banks 1,3): need src L-4 -> row_shr:4 (0x114)
__device__ __forceinline__ float dpp_xor4(float v) {
    int t = __builtin_amdgcn_update_dpp(__float_as_int(v), __float_as_int(v),
                                        0x104 /*row_shl:4*/, 0xF, 0x5, false);
    t = __builtin_amdgcn_update_dpp(t, __float_as_int(v),
                                    0x114 /*row_shr:4*/, 0xF, 0xA, false);
    return __int_as_float(t);
}

// DPP-modified FMAC: c += dpp<perm>(s) * w. src0 carries the DPP modifier.
#define FMAC_DPP_X1(c, s, w)                                                  \
    asm("v_fmac_f32_dpp %0, %1, %2 quad_perm:[1,0,3,2] row_mask:0xf "         \
        "bank_mask:0xf" : "+v"(c) : "v"(s), "v"(w))
#define FMAC_DPP_X2(c, s, w)                                                  \
    asm("v_fmac_f32_dpp %0, %1, %2 quad_perm:[2,3,0,1] row_mask:0xf "         \
        "bank_mask:0xf" : "+v"(c) : "v"(s), "v"(w))
#define FMAC_DPP_X3(c, s, w)                                                  \
    asm("v_fmac_f32_dpp %0, %1, %2 quad_perm:[3,2,1,0] row_mask:0xf "         \
        "bank_mask:0xf" : "+v"(c) : "v"(s), "v"(w))

__global__ __launch_bounds__(64, 1) void rnn_fused(
    const float* __restrict__ x,      // [B, T, 2]
    const float* __restrict__ W_ih,   // [20, 2]
    const float* __restrict__ W_hh,   // [20, 20]
    const float* __restrict__ b_ih,   // [20]
    const float* __restrict__ b_hh,   // [20]
    const float* __restrict__ fc_w,   // [1, 20]
    const float* __restrict__ fc_b,   // [1]
    float* __restrict__ out)          // [8192] out, then [8192*20] h_state
{
    const int lane = threadIdx.x & 63;
    const int g    = lane & 7;        // owns j = 3g..3g+2
    const int r    = lane >> 3;       // row within wave
    const int row  = blockIdx.x * 8 + r;

    // W[jj][m][kk] = W_hh[j, k] with j = 3g+jj, k = 3(g^m)+kk (0 if OOB).
    float W[3][8][3];
    float wi0[3], wi1[3], bsum[3], fcw[3];
#pragma unroll
    for (int jj = 0; jj < 3; ++jj) {
        const int j = 3 * g + jj;
        const bool v = (j < 20);
#pragma unroll
        for (int m = 0; m < 8; ++m) {
#pragma unroll
            for (int kk = 0; kk < 3; ++kk) {
                const int k = 3 * (g ^ m) + kk;
                W[jj][m][kk] = (v && k < 20) ? W_hh[j * 20 + k] : 0.0f;
            }
        }
        wi0[jj]  = v ? W_ih[j * 2 + 0] : 0.0f;
        wi1[jj]  = v ? W_ih[j * 2 + 1] : 0.0f;
        bsum[jj] = v ? (b_ih[j] + b_hh[j]) : 0.0f;
        fcw[jj]  = v ? fc_w[j] : 0.0f;
    }

    float h[3]  = {0.0f, 0.0f, 0.0f};   // own h_j
    float g4[3] = {0.0f, 0.0f, 0.0f};   // h of group g^4

    auto step = [&](float x0, float x1) {
        float c0 = fmaf(x1, wi1[0], fmaf(x0, wi0[0], bsum[0]));
        float c1 = fmaf(x1, wi1[1], fmaf(x0, wi0[1], bsum[1]));
        float c2 = fmaf(x1, wi1[2], fmaf(x0, wi0[2], bsum[2]));
        // m=0 (own) and m=4 (g4): plain fmacs -- also the hazard spacer
        // between last step's h/g4 writes and the first asm dpp reader.
#pragma unroll
        for (int kk = 0; kk < 3; ++kk) {
            c0 = fmaf(h[kk],  W[0][0][kk], c0);
            c1 = fmaf(h[kk],  W[1][0][kk], c1);
            c2 = fmaf(h[kk],  W[2][0][kk], c2);
            c0 = fmaf(g4[kk], W[0][4][kk], c0);
            c1 = fmaf(g4[kk], W[1][4][kk], c1);
            c2 = fmaf(g4[kk], W[2][4][kk], c2);
        }
        // m=1..3 from h via quad_perm on the fmac (free permute):
#pragma unroll
        for (int kk = 0; kk < 3; ++kk) {
            FMAC_DPP_X1(c0, h[kk], W[0][1][kk]);
            FMAC_DPP_X1(c1, h[kk], W[1][1][kk]);
            FMAC_DPP_X1(c2, h[kk], W[2][1][kk]);
        }
#pragma unroll
        for (int kk = 0; kk < 3; ++kk) {
            FMAC_DPP_X2(c0, h[kk], W[0][2][kk]);
            FMAC_DPP_X2(c1, h[kk], W[1][2][kk]);
            FMAC_DPP_X2(c2, h[kk], W[2][2][kk]);
        }
#pragma unroll
        for (int kk = 0; kk < 3; ++kk) {
            FMAC_DPP_X3(c0, h[kk], W[0][3][kk]);
            FMAC_DPP_X3(c1, h[kk], W[1][3][kk]);
            FMAC_DPP_X3(c2, h[kk], W[2][3][kk]);
        }
        // m=5..7 from g4 via quad_perm ((g^4)^qm = g^(4+qm)):
#pragma unroll
        for (int kk = 0; kk < 3; ++kk) {
            FMAC_DPP_X1(c0, g4[kk], W[0][5][kk]);
            FMAC_DPP_X1(c1, g4[kk], W[1][5][kk]);
            FMAC_DPP_X1(c2, g4[kk], W[2][5][kk]);
        }
#pragma unroll
        for (int kk = 0; kk < 3; ++kk) {
            FMAC_DPP_X2(c0, g4[kk], W[0][6][kk]);
            FMAC_DPP_X2(c1, g4[kk], W[1][6][kk]);
            FMAC_DPP_X2(c2, g4[kk], W[2][6][kk]);
        }
#pragma unroll
        for (int kk = 0; kk < 3; ++kk) {
            FMAC_DPP_X3(c0, g4[kk], W[0][7][kk]);
            FMAC_DPP_X3(c1, g4[kk], W[1][7][kk]);
            FMAC_DPP_X3(c2, g4[kk], W[2][7][kk]);
        }
        // new h + the single remaining gather stage (intrinsic: compiler
        // inserts any required hazard nops here).
        h[0] = tanh_fast(c0);
        h[1] = tanh_fast(c1);
        h[2] = tanh_fast(c2);
        g4[0] = dpp_xor4(h[0]);
        g4[1] = dpp_xor4(h[1]);
        g4[2] = dpp_xor4(h[2]);
    };

    // x: per 8-step chunk, 4 float4 per lane (octet shares the cacheline, L1
    // broadcast); double-buffered one chunk ahead, ping-pong q/qn (no copies).
    const float4* xq = (const float4*)(x + (size_t)row * (T_STEPS * 2));
    float4 q[4], qn[4];
#pragma unroll
    for (int i = 0; i < 4; ++i) q[i] = xq[i];

#pragma unroll 1
    for (int c = 0; c < NCHUNK; c += 2) {
        const int c1 = c + 1;                                  // qn <- chunk c+1
        const int c2 = (c + 2 < NCHUNK) ? (c + 2) : c1;        // q  <- chunk c+2
#pragma unroll
        for (int i = 0; i < 4; ++i) qn[i] = xq[4 * c1 + i];

        step(q[0].x, q[0].y); step(q[0].z, q[0].w);
        step(q[1].x, q[1].y); step(q[1].z, q[1].w);
        step(q[2].x, q[2].y); step(q[2].z, q[2].w);
        step(q[3].x, q[3].y); step(q[3].z, q[3].w);

#pragma unroll
        for (int i = 0; i < 4; ++i) q[i] = xq[4 * c2 + i];

        step(qn[0].x, qn[0].y); step(qn[0].z, qn[0].w);
        step(qn[1].x, qn[1].y); step(qn[1].z, qn[1].w);
        step(qn[2].x, qn[2].y); step(qn[2].z, qn[2].w);
        step(qn[3].x, qn[3].y); step(qn[3].z, qn[3].w);
    }

    // ---- epilogue ----
    // h_state: [1, B, H] flat at offset B_ROWS; lane stores its own 3 j's
    {
        const int j0 = 3 * g;
        float* hs = out + B_ROWS + (size_t)row * 20;
        if (j0 + 0 < 20) hs[j0 + 0] = h[0];
        if (j0 + 1 < 20) hs[j0 + 1] = h[1];
        if (j0 + 2 < 20) hs[j0 + 2] = h[2];
    }
    // FC: per-lane partial over own j's, octet tree-reduce (xor1,xor2,mir7)
    {
        float p = h[0] * fcw[0];
        p = fmaf(h[1], fcw[1], p);
        p = fmaf(h[2], fcw[2], p);
        p += dpp_full<XOR1_CTRL>(p);
        p += dpp_full<XOR2_CTRL>(p);
        p += dpp_full<MIR7_CTRL>(p);
        if (g == 0) out[row] = p + fc_b[0];
    }
}

extern "C" void kernel_launch(void* const* d_in, const int* in_sizes, int n_in,
                              void* d_out, int out_size, void* d_ws, size_t ws_size,
                              hipStream_t stream) {
    const float* x    = (const float*)d_in[0];
    const float* W_ih = (const float*)d_in[1];
    const float* W_hh = (const float*)d_in[2];
    const float* b_ih = (const float*)d_in[3];
    const float* b_hh = (const float*)d_in[4];
    const float* fc_w = (const float*)d_in[5];
    const float* fc_b = (const float*)d_in[6];
    float* out = (float*)d_out;

    // 1024 blocks x 64 threads: 1 wave/block, 8 rows/wave -> 1 wave/SIMD
    rnn_fused<<<1024, 64, 0, stream>>>(x, W_ih, W_hh, b_ih, b_hh, fc_w, fc_b, out);
}

// Round 6
// 545.163 us; speedup vs baseline: 1.7008x; 1.1784x over previous
//
#include <hip/hip_runtime.h>

// Tanh-RNN: B=8192, T=2048, I=2, H=20, FC(H->1) on last h.
// Round 13: R8 structure (j-split: 8 lanes/row, 3 j/lane, 8 rows/wave, 1024
// waves = 1/SIMD; h-allgather = 21 single-DPP butterfly mir7->xor1->xor2)
// with the 72-FMA block forced onto packed FP32:
//   v_pk_fma_f32 (VOP3P, CDNA dual-FP32, full rate) = 2 FMA/lane/instr.
// R8's fma2(hp, W2, c) is exactly elementwise pk_fma; measured busy says the
// compiler wasn't emitting it, so inline asm it. 72 fma -> 36 pk (-72cy/step),
// c-init 6 -> 3 pk (-6cy). Butterfly DPP movs write directly into .x/.y
// halves of persistent f32x2 pairs (tied old operand, no repack movs).
// Numerics bit-identical to R8 (same pairing, same order): absmax must stay
// 0.001953125.
// Cost model (calibrated R8/R12): DPP op ~5cy, plain VALU 2cy, trans 8cy.

#define T_STEPS 2048
#define B_ROWS  8192
#define NCHUNK  (T_STEPS / 8)

#define XOR1_CTRL 0xB1   // quad_perm(1,0,3,2): lane^1
#define XOR2_CTRL 0x4E   // quad_perm(2,3,0,1): lane^2
#define MIR7_CTRL 0x141  // row_half_mirror: lane^7 within each 8-lane octet

typedef float f32x2 __attribute__((ext_vector_type(2)));

__device__ __forceinline__ float tanh_fast(float a) {
    // tanh(a) = 1 - 2/(exp(2a)+1); exp(2a)=exp2(a*2*log2e). Saturates correctly.
    float e = __builtin_amdgcn_exp2f(a * 2.8853900817779268f);
    float r = __builtin_amdgcn_rcpf(e + 1.0f);
    return fmaf(-2.0f, r, 1.0f);
}

// Tied-DPP: returns dpp(src); 'old' is the dest's dead current value so the
// tied-def of v_mov_b32_dpp costs no extra mov. Full masks, bound_ctrl=false.
template <int CTRL>
__device__ __forceinline__ float dpp_t(float old_, float src) {
    return __int_as_float(__builtin_amdgcn_update_dpp(
        __float_as_int(old_), __float_as_int(src), CTRL, 0xF, 0xF, false));
}

// Epilogue-only variant (old=0, bound_ctrl=true) -- executed once.
template <int CTRL>
__device__ __forceinline__ float dpp_full(float v) {
    return __int_as_float(__builtin_amdgcn_update_dpp(
        0, __float_as_int(v), CTRL, 0xF, 0xF, true));
}

// c += a * b, packed fp32 (both halves). Default VOP3P modifiers = elementwise.
__device__ __forceinline__ void pk_fma_acc(f32x2& c, f32x2 a, f32x2 b) {
    asm("v_pk_fma_f32 %0, %1, %2, %0" : "+v"(c) : "v"(a), "v"(b));
}
// d = a * b + c, packed fp32.
__device__ __forceinline__ f32x2 pk_fma3(f32x2 a, f32x2 b, f32x2 c) {
    f32x2 d;
    asm("v_pk_fma_f32 %0, %1, %2, %3" : "=v"(d) : "v"(a), "v"(b), "v"(c));
    return d;
}

__global__ __launch_bounds__(64, 1) void rnn_fused(
    const float* __restrict__ x,      // [B, T, 2]
    const float* __restrict__ W_ih,   // [20, 2]
    const float* __restrict__ W_hh,   // [20, 20]
    const float* __restrict__ b_ih,   // [20]
    const float* __restrict__ b_hh,   // [20]
    const float* __restrict__ fc_w,   // [1, 20]
    const float* __restrict__ fc_b,   // [1]
    float* __restrict__ out)          // [8192] out, then [8192*20] h_state
{
    const int lane = threadIdx.x & 63;
    const int g    = lane & 7;        // owns j = 3g..3g+2
    const int r    = lane >> 3;       // row within wave
    const int row  = blockIdx.x * 8 + r;

    // Butterfly slot order (stages mir7, xor1, xor2): slot s holds h of
    // j = 3*(g^M[s/3]) + (s%3), M as below. Slot s lives in hp[s/2] half s&1.
    const int M[8] = {0, 7, 1, 6, 2, 5, 3, 4};

    f32x2 W2[3][12];                  // pair p covers slots 2p, 2p+1
    f32x2 wiP[3], bP[3];
    float fcw[3];
#pragma unroll
    for (int jj = 0; jj < 3; ++jj) {
        const int j = 3 * g + jj;
        const bool v = (j < 20);
#pragma unroll
        for (int p = 0; p < 12; ++p) {
            float wv[2];
#pragma unroll
            for (int h = 0; h < 2; ++h) {
                const int slot = 2 * p + h;
                const int k = 3 * (g ^ M[slot / 3]) + (slot % 3);
                wv[h] = (v && k < 20) ? W_hh[j * 20 + k] : 0.0f;
            }
            W2[jj][p].x = wv[0];
            W2[jj][p].y = wv[1];
        }
        wiP[jj].x = v ? W_ih[j * 2 + 0] : 0.0f;
        wiP[jj].y = v ? W_ih[j * 2 + 1] : 0.0f;
        bP[jj].x  = v ? (b_ih[j] + b_hh[j]) : 0.0f;
        bP[jj].y  = 0.0f;
        fcw[jj]   = v ? fc_w[j] : 0.0f;
    }

    f32x2 hp[12];                     // gathered h, butterfly slot order
#pragma unroll
    for (int i = 0; i < 12; ++i) { hp[i].x = 0.0f; hp[i].y = 0.0f; }

    auto step = [&](float x0, float x1) {
        f32x2 xp; xp.x = x0; xp.y = x1;
        f32x2 c0 = pk_fma3(xp, wiP[0], bP[0]);   // (x0*wi0+bsum, x1*wi1)
        f32x2 c1 = pk_fma3(xp, wiP[1], bP[1]);
        f32x2 c2 = pk_fma3(xp, wiP[2], bP[2]);
#pragma unroll
        for (int p = 0; p < 12; ++p) {
            pk_fma_acc(c0, hp[p], W2[0][p]);
            pk_fma_acc(c1, hp[p], W2[1][p]);
            pk_fma_acc(c2, hp[p], W2[2][p]);
        }
        const float h0 = tanh_fast(c0.x + c0.y);
        const float h1 = tanh_fast(c1.x + c1.y);
        const float h2 = tanh_fast(c2.x + c2.y);
        // ---- DPP butterfly allgather: 21 single-DPP movs into pair halves ----
        hp[0].x = h0; hp[0].y = h1; hp[1].x = h2;
        hp[1].y = dpp_t<MIR7_CTRL>(hp[1].y, hp[0].x);
        hp[2].x = dpp_t<MIR7_CTRL>(hp[2].x, hp[0].y);
        hp[2].y = dpp_t<MIR7_CTRL>(hp[2].y, hp[1].x);
        hp[3].x = dpp_t<XOR1_CTRL>(hp[3].x, hp[0].x);
        hp[3].y = dpp_t<XOR1_CTRL>(hp[3].y, hp[0].y);
        hp[4].x = dpp_t<XOR1_CTRL>(hp[4].x, hp[1].x);
        hp[4].y = dpp_t<XOR1_CTRL>(hp[4].y, hp[1].y);
        hp[5].x = dpp_t<XOR1_CTRL>(hp[5].x, hp[2].x);
        hp[5].y = dpp_t<XOR1_CTRL>(hp[5].y, hp[2].y);
        hp[6].x  = dpp_t<XOR2_CTRL>(hp[6].x,  hp[0].x);
        hp[6].y  = dpp_t<XOR2_CTRL>(hp[6].y,  hp[0].y);
        hp[7].x  = dpp_t<XOR2_CTRL>(hp[7].x,  hp[1].x);
        hp[7].y  = dpp_t<XOR2_CTRL>(hp[7].y,  hp[1].y);
        hp[8].x  = dpp_t<XOR2_CTRL>(hp[8].x,  hp[2].x);
        hp[8].y  = dpp_t<XOR2_CTRL>(hp[8].y,  hp[2].y);
        hp[9].x  = dpp_t<XOR2_CTRL>(hp[9].x,  hp[3].x);
        hp[9].y  = dpp_t<XOR2_CTRL>(hp[9].y,  hp[3].y);
        hp[10].x = dpp_t<XOR2_CTRL>(hp[10].x, hp[4].x);
        hp[10].y = dpp_t<XOR2_CTRL>(hp[10].y, hp[4].y);
        hp[11].x = dpp_t<XOR2_CTRL>(hp[11].x, hp[5].x);
        hp[11].y = dpp_t<XOR2_CTRL>(hp[11].y, hp[5].y);
    };

    // x: per 8-step chunk, 4 float4 per lane (octet shares the cacheline, L1
    // broadcast); double-buffered one chunk ahead, ping-pong q/qn (no copies).
    const float4* xq = (const float4*)(x + (size_t)row * (T_STEPS * 2));
    float4 q[4], qn[4];
#pragma unroll
    for (int i = 0; i < 4; ++i) q[i] = xq[i];

#pragma unroll 1
    for (int c = 0; c < NCHUNK; c += 2) {
        const int c1 = c + 1;                                  // qn <- chunk c+1
        const int c2 = (c + 2 < NCHUNK) ? (c + 2) : c1;        // q  <- chunk c+2
#pragma unroll
        for (int i = 0; i < 4; ++i) qn[i] = xq[4 * c1 + i];

        step(q[0].x, q[0].y); step(q[0].z, q[0].w);
        step(q[1].x, q[1].y); step(q[1].z, q[1].w);
        step(q[2].x, q[2].y); step(q[2].z, q[2].w);
        step(q[3].x, q[3].y); step(q[3].z, q[3].w);

#pragma unroll
        for (int i = 0; i < 4; ++i) q[i] = xq[4 * c2 + i];

        step(qn[0].x, qn[0].y); step(qn[0].z, qn[0].w);
        step(qn[1].x, qn[1].y); step(qn[1].z, qn[1].w);
        step(qn[2].x, qn[2].y); step(qn[2].z, qn[2].w);
        step(qn[3].x, qn[3].y); step(qn[3].z, qn[3].w);
    }

    // ---- epilogue ----
    // h_state: [1, B, H] flat at offset B_ROWS; lane stores its own 3 j's
    // (slots 0..2 = hp[0].x, hp[0].y, hp[1].x).
    {
        const int j0 = 3 * g;
        float* hs = out + B_ROWS + (size_t)row * 20;
        if (j0 + 0 < 20) hs[j0 + 0] = hp[0].x;
        if (j0 + 1 < 20) hs[j0 + 1] = hp[0].y;
        if (j0 + 2 < 20) hs[j0 + 2] = hp[1].x;
    }
    // FC: per-lane partial over own j's, octet tree-reduce (xor1,xor2,mir7)
    {
        float p = hp[0].x * fcw[0];
        p = fmaf(hp[0].y, fcw[1], p);
        p = fmaf(hp[1].x, fcw[2], p);
        p += dpp_full<XOR1_CTRL>(p);
        p += dpp_full<XOR2_CTRL>(p);
        p += dpp_full<MIR7_CTRL>(p);
        if (g == 0) out[row] = p + fc_b[0];
    }
}

extern "C" void kernel_launch(void* const* d_in, const int* in_sizes, int n_in,
                              void* d_out, int out_size, void* d_ws, size_t ws_size,
                              hipStream_t stream) {
    const float* x    = (const float*)d_in[0];
    const float* W_ih = (const float*)d_in[1];
    const float* W_hh = (const float*)d_in[2];
    const float* b_ih = (const float*)d_in[3];
    const float* b_hh = (const float*)d_in[4];
    const float* fc_w = (const float*)d_in[5];
    const float* fc_b = (const float*)d_in[6];
    float* out = (float*)d_out;

    // 1024 blocks x 64 threads: 1 wave/block, 8 rows/wave -> 1 wave/SIMD
    rnn_fused<<<1024, 64, 0, stream>>>(x, W_ih, W_hh, b_ih, b_hh, fc_w, fc_b, out);
}

// Round 7
// 535.415 us; speedup vs baseline: 1.7317x; 1.0182x over previous
//
#include <hip/hip_runtime.h>

// Tanh-RNN: B=8192, T=2048, I=2, H=20, FC(H->1) on last h.
// Round 14: R13's pk_fma + DPP butterfly, SOFTWARE-PIPELINED. Work is
// bit-identical to R13 (absmax must stay 0.001953125); only the schedule
// changes: the 21-DPP butterfly of step t's h is interleaved INTO step
// t+1's pk-FMA block by readiness order:
//   pk p=0 needs hp[0] only (tanh outs, no DPP)
//   pk p=1,2 need stage-1 (mir7 x3)
//   pk p=3..5 need stage-2 (xor1 x6)
//   pk p=6..11 need stage-3 (xor2 x12)
// so per step: c-init; mir7; pk0; xor1; pk1-2; xor2; pk3-11; adds; tanh
// (tanh writes hp[0].x/.y, hp[1].x directly -- no repack movs).
// This hides DPP stage latency + read-after-VALU-write hazard slots (s_nop,
// invisible to VALUBusy) under pk issue. R13 exposed ~152 cy/step of stall.
// Cost model (calibrated R8/R12/R13): pk ~2.5cy, DPP ~8cy, trans ~8cy.

#define T_STEPS 2048
#define B_ROWS  8192
#define NCHUNK  (T_STEPS / 8)

#define XOR1_CTRL 0xB1   // quad_perm(1,0,3,2): lane^1
#define XOR2_CTRL 0x4E   // quad_perm(2,3,0,1): lane^2
#define MIR7_CTRL 0x141  // row_half_mirror: lane^7 within each 8-lane octet

typedef float f32x2 __attribute__((ext_vector_type(2)));

__device__ __forceinline__ float tanh_fast(float a) {
    // tanh(a) = 1 - 2/(exp(2a)+1); exp(2a)=exp2(a*2*log2e). Saturates correctly.
    float e = __builtin_amdgcn_exp2f(a * 2.8853900817779268f);
    float r = __builtin_amdgcn_rcpf(e + 1.0f);
    return fmaf(-2.0f, r, 1.0f);
}

// Tied-DPP: returns dpp(src); 'old' is the dest's dead current value so the
// tied-def of v_mov_b32_dpp costs no extra mov. Full masks, bound_ctrl=false.
template <int CTRL>
__device__ __forceinline__ float dpp_t(float old_, float src) {
    return __int_as_float(__builtin_amdgcn_update_dpp(
        __float_as_int(old_), __float_as_int(src), CTRL, 0xF, 0xF, false));
}

// Epilogue-only variant (old=0, bound_ctrl=true) -- executed once.
template <int CTRL>
__device__ __forceinline__ float dpp_full(float v) {
    return __int_as_float(__builtin_amdgcn_update_dpp(
        0, __float_as_int(v), CTRL, 0xF, 0xF, true));
}

// c += a * b, packed fp32 (both halves). Default VOP3P modifiers = elementwise.
__device__ __forceinline__ void pk_fma_acc(f32x2& c, f32x2 a, f32x2 b) {
    asm("v_pk_fma_f32 %0, %1, %2, %0" : "+v"(c) : "v"(a), "v"(b));
}
// d = a * b + c, packed fp32.
__device__ __forceinline__ f32x2 pk_fma3(f32x2 a, f32x2 b, f32x2 c) {
    f32x2 d;
    asm("v_pk_fma_f32 %0, %1, %2, %3" : "=v"(d) : "v"(a), "v"(b), "v"(c));
    return d;
}

__global__ __launch_bounds__(64, 1) void rnn_fused(
    const float* __restrict__ x,      // [B, T, 2]
    const float* __restrict__ W_ih,   // [20, 2]
    const float* __restrict__ W_hh,   // [20, 20]
    const float* __restrict__ b_ih,   // [20]
    const float* __restrict__ b_hh,   // [20]
    const float* __restrict__ fc_w,   // [1, 20]
    const float* __restrict__ fc_b,   // [1]
    float* __restrict__ out)          // [8192] out, then [8192*20] h_state
{
    const int lane = threadIdx.x & 63;
    const int g    = lane & 7;        // owns j = 3g..3g+2
    const int r    = lane >> 3;       // row within wave
    const int row  = blockIdx.x * 8 + r;

    // Butterfly slot order (stages mir7, xor1, xor2): slot s holds h of
    // j = 3*(g^M[s/3]) + (s%3), M as below. Slot s lives in hp[s/2] half s&1.
    const int M[8] = {0, 7, 1, 6, 2, 5, 3, 4};

    f32x2 W2[3][12];                  // pair p covers slots 2p, 2p+1
    f32x2 wiP[3], bP[3];
    float fcw[3];
#pragma unroll
    for (int jj = 0; jj < 3; ++jj) {
        const int j = 3 * g + jj;
        const bool v = (j < 20);
#pragma unroll
        for (int p = 0; p < 12; ++p) {
            float wv[2];
#pragma unroll
            for (int h = 0; h < 2; ++h) {
                const int slot = 2 * p + h;
                const int k = 3 * (g ^ M[slot / 3]) + (slot % 3);
                wv[h] = (v && k < 20) ? W_hh[j * 20 + k] : 0.0f;
            }
            W2[jj][p].x = wv[0];
            W2[jj][p].y = wv[1];
        }
        wiP[jj].x = v ? W_ih[j * 2 + 0] : 0.0f;
        wiP[jj].y = v ? W_ih[j * 2 + 1] : 0.0f;
        bP[jj].x  = v ? (b_ih[j] + b_hh[j]) : 0.0f;
        bP[jj].y  = 0.0f;
        fcw[jj]   = v ? fc_w[j] : 0.0f;
    }

    // hp: gathered h in butterfly slot order. tanh of step t writes
    // hp[0].x/.y, hp[1].x directly; the butterfly (mir7/xor1/xor2) runs at
    // the START of step t+1, interleaved with its pk consumers.
    f32x2 hp[12];
#pragma unroll
    for (int i = 0; i < 12; ++i) { hp[i].x = 0.0f; hp[i].y = 0.0f; }

    auto step = [&](float x0, float x1) {
        f32x2 xp; xp.x = x0; xp.y = x1;
        // c-init (x only, independent of h)
        f32x2 c0 = pk_fma3(xp, wiP[0], bP[0]);   // (x0*wi0+bsum, x1*wi1)
        f32x2 c1 = pk_fma3(xp, wiP[1], bP[1]);
        f32x2 c2 = pk_fma3(xp, wiP[2], bP[2]);
        // stage 1: mir7 (reads tanh outputs of previous step)
        hp[1].y = dpp_t<MIR7_CTRL>(hp[1].y, hp[0].x);
        hp[2].x = dpp_t<MIR7_CTRL>(hp[2].x, hp[0].y);
        hp[2].y = dpp_t<MIR7_CTRL>(hp[2].y, hp[1].x);
        // pk p=0 (needs hp[0] only)
        pk_fma_acc(c0, hp[0], W2[0][0]);
        pk_fma_acc(c1, hp[0], W2[1][0]);
        pk_fma_acc(c2, hp[0], W2[2][0]);
        // stage 2: xor1 (reads hp[0..2])
        hp[3].x = dpp_t<XOR1_CTRL>(hp[3].x, hp[0].x);
        hp[3].y = dpp_t<XOR1_CTRL>(hp[3].y, hp[0].y);
        hp[4].x = dpp_t<XOR1_CTRL>(hp[4].x, hp[1].x);
        hp[4].y = dpp_t<XOR1_CTRL>(hp[4].y, hp[1].y);
        hp[5].x = dpp_t<XOR1_CTRL>(hp[5].x, hp[2].x);
        hp[5].y = dpp_t<XOR1_CTRL>(hp[5].y, hp[2].y);
        // pk p=1,2 (need stage-1 results)
        pk_fma_acc(c0, hp[1], W2[0][1]);
        pk_fma_acc(c1, hp[1], W2[1][1]);
        pk_fma_acc(c2, hp[1], W2[2][1]);
        pk_fma_acc(c0, hp[2], W2[0][2]);
        pk_fma_acc(c1, hp[2], W2[1][2]);
        pk_fma_acc(c2, hp[2], W2[2][2]);
        // stage 3: xor2 (reads hp[0..5])
        hp[6].x  = dpp_t<XOR2_CTRL>(hp[6].x,  hp[0].x);
        hp[6].y  = dpp_t<XOR2_CTRL>(hp[6].y,  hp[0].y);
        hp[7].x  = dpp_t<XOR2_CTRL>(hp[7].x,  hp[1].x);
        hp[7].y  = dpp_t<XOR2_CTRL>(hp[7].y,  hp[1].y);
        hp[8].x  = dpp_t<XOR2_CTRL>(hp[8].x,  hp[2].x);
        hp[8].y  = dpp_t<XOR2_CTRL>(hp[8].y,  hp[2].y);
        hp[9].x  = dpp_t<XOR2_CTRL>(hp[9].x,  hp[3].x);
        hp[9].y  = dpp_t<XOR2_CTRL>(hp[9].y,  hp[3].y);
        hp[10].x = dpp_t<XOR2_CTRL>(hp[10].x, hp[4].x);
        hp[10].y = dpp_t<XOR2_CTRL>(hp[10].y, hp[4].y);
        hp[11].x = dpp_t<XOR2_CTRL>(hp[11].x, hp[5].x);
        hp[11].y = dpp_t<XOR2_CTRL>(hp[11].y, hp[5].y);
        // pk p=3..5 (need stage-2), p=6..11 (need stage-3)
#pragma unroll
        for (int p = 3; p < 12; ++p) {
            pk_fma_acc(c0, hp[p], W2[0][p]);
            pk_fma_acc(c1, hp[p], W2[1][p]);
            pk_fma_acc(c2, hp[p], W2[2][p]);
        }
        // pair-sum + tanh, written straight into next step's hp[0]/hp[1].x
        hp[0].x = tanh_fast(c0.x + c0.y);
        hp[0].y = tanh_fast(c1.x + c1.y);
        hp[1].x = tanh_fast(c2.x + c2.y);
    };

    // x: per 8-step chunk, 4 float4 per lane (octet shares the cacheline, L1
    // broadcast); double-buffered one chunk ahead, ping-pong q/qn (no copies).
    const float4* xq = (const float4*)(x + (size_t)row * (T_STEPS * 2));
    float4 q[4], qn[4];
#pragma unroll
    for (int i = 0; i < 4; ++i) q[i] = xq[i];

#pragma unroll 1
    for (int c = 0; c < NCHUNK; c += 2) {
        const int c1 = c + 1;                                  // qn <- chunk c+1
        const int c2 = (c + 2 < NCHUNK) ? (c + 2) : c1;        // q  <- chunk c+2
#pragma unroll
        for (int i = 0; i < 4; ++i) qn[i] = xq[4 * c1 + i];

        step(q[0].x, q[0].y); step(q[0].z, q[0].w);
        step(q[1].x, q[1].y); step(q[1].z, q[1].w);
        step(q[2].x, q[2].y); step(q[2].z, q[2].w);
        step(q[3].x, q[3].y); step(q[3].z, q[3].w);

#pragma unroll
        for (int i = 0; i < 4; ++i) q[i] = xq[4 * c2 + i];

        step(qn[0].x, qn[0].y); step(qn[0].z, qn[0].w);
        step(qn[1].x, qn[1].y); step(qn[1].z, qn[1].w);
        step(qn[2].x, qn[2].y); step(qn[2].z, qn[2].w);
        step(qn[3].x, qn[3].y); step(qn[3].z, qn[3].w);
    }

    // ---- epilogue ----
    // h_state: [1, B, H] flat at offset B_ROWS; lane stores its own 3 j's
    // (tanh outputs live in hp[0].x, hp[0].y, hp[1].x; no trailing butterfly
    // was run after the last step -- not needed).
    {
        const int j0 = 3 * g;
        float* hs = out + B_ROWS + (size_t)row * 20;
        if (j0 + 0 < 20) hs[j0 + 0] = hp[0].x;
        if (j0 + 1 < 20) hs[j0 + 1] = hp[0].y;
        if (j0 + 2 < 20) hs[j0 + 2] = hp[1].x;
    }
    // FC: per-lane partial over own j's, octet tree-reduce (xor1,xor2,mir7)
    {
        float p = hp[0].x * fcw[0];
        p = fmaf(hp[0].y, fcw[1], p);
        p = fmaf(hp[1].x, fcw[2], p);
        p += dpp_full<XOR1_CTRL>(p);
        p += dpp_full<XOR2_CTRL>(p);
        p += dpp_full<MIR7_CTRL>(p);
        if (g == 0) out[row] = p + fc_b[0];
    }
}

extern "C" void kernel_launch(void* const* d_in, const int* in_sizes, int n_in,
                              void* d_out, int out_size, void* d_ws, size_t ws_size,
                              hipStream_t stream) {
    const float* x    = (const float*)d_in[0];
    const float* W_ih = (const float*)d_in[1];
    const float* W_hh = (const float*)d_in[2];
    const float* b_ih = (const float*)d_in[3];
    const float* b_hh = (const float*)d_in[4];
    const float* fc_w = (const float*)d_in[5];
    const float* fc_b = (const float*)d_in[6];
    float* out = (float*)d_out;

    // 1024 blocks x 64 threads: 1 wave/block, 8 rows/wave -> 1 wave/SIMD
    rnn_fused<<<1024, 64, 0, stream>>>(x, W_ih, W_hh, b_ih, b_hh, fc_w, fc_b, out);
}